// Round 9
// baseline (209.610 us; speedup 1.0000x reference)
//
#include <hip/hip_runtime.h>
#include <hip/hip_bf16.h>
#include <stdint.h>

// Problem constants (B=8, S=2048, E=1024, H=128, DK=8)
#define M_DIM 16384   // B*S
#define N_DIM 1024    // E (output features)
#define K_DIM 1024    // E (reduction)

typedef __attribute__((ext_vector_type(8))) short short8;
typedef __attribute__((ext_vector_type(4))) float f32x4;

// async global->LDS, 16B per lane. LDS dest must be wave-uniform base + lane*16.
#define GLD_LDS(g, l) __builtin_amdgcn_global_load_lds( \
    (const __attribute__((address_space(1))) unsigned int*)(g), \
    (__attribute__((address_space(3))) unsigned int*)(l), 16, 0, 0)

__device__ __forceinline__ unsigned short f2bf(float f) {
  union { float f; unsigned int u; } v;
  v.f = f;
  unsigned int u = v.u + 0x7FFFu + ((v.u >> 16) & 1u);  // RNE
  return (unsigned short)(u >> 16);
}

// W -> bf16 cast only (6 MB traffic, ~2 us). A-prep is fused into the GEMM.
#define PREP_W_BLOCKS (N_DIM * K_DIM / (256 * 8))   // 512
__global__ __launch_bounds__(256) void prep_w(const float* __restrict__ W,
                                              unsigned short* __restrict__ Wb) {
  const long i = ((long)blockIdx.x * 256 + threadIdx.x) * 8;
  float4 w0 = *(const float4*)(W + i);
  float4 w1 = *(const float4*)(W + i + 4);
  union { unsigned short s[8]; short8 v; } o;
  o.s[0] = f2bf(w0.x); o.s[1] = f2bf(w0.y); o.s[2] = f2bf(w0.z); o.s[3] = f2bf(w0.w);
  o.s[4] = f2bf(w1.x); o.s[5] = f2bf(w1.y); o.s[6] = f2bf(w1.z); o.s[7] = f2bf(w1.w);
  *(short8*)(Wb + i) = o.v;
}

// C[m,n] = sum_k cos(x[m,k]+theta[k]) * Wb[n,k] + bias[n].
//
// R10 fused v4 = r8 (correct on HW) + IR-LEVEL LOAD PIN.
// Diagnosis chain: r7/r8 VGPR=84/88 (vs ~180 live-if-pinned) => the x prefetch
// loads SANK below CONVA/COMPUTE (legal: global loads don't alias LDS ds ops;
// sched_barrier(0) is machine-level only, IR sinking walked past it). The only
// fence they couldn't cross was the NEXT iter's vmcnt "memory" asm -> loads
// ended up just before their own wait = zero overlap, full latency per tile.
// r9's asm-load fix crashed (missing early-clobber => dst/addr reg overlap).
// Fix here: plain loads + asm volatile("" ::: "memory") IMMEDIATELY after the
// issue group. A global load cannot sink past a may-write-memory asm, and the
// fence forces no waitcnt (values not consumed there) -> loads stay async at
// the top of the iteration. Theta for t+1 is prefetched in the same pinned
// group. Verification signal: VGPR_Count ~180-200 (if ~85, fence failed).
//
// Body (tile t, parity p, xa/th sets E/O alternate; x2 unrolled, static regs):
//   VMW0()            // xa(t),th(t) regs + own STAGEB(t) drained
//   __syncthreads()   // all waves' STAGEB(t) visible
//   LOADX(t+1 -> other set) ; STAGEB(p^1, t+1) ; FENCE ; sched_barrier(0)
//   CONVA(t)          // af = bf16(cos(xa+th)), ~300cy VALU
//   COMPUTE(p)        // 16 ds_read_b128 + 32 MFMA (vs reg af)
// Races (r8-proven): Bs[p] visible post-sync (each wave VMW0s own stages
// pre-bar); Bs[p^1] overwrite post-sync(t) vs COMPUTE(t-1) readers pre-sync(t)
// -> safe. E/O sets disjoint -> no WAR on xa across iterations.
//
// Tile 128x128, 4 waves (wave 32M x 128N -> all A-rows unique per block, cos
// once per element per block). LDS = B only, 32 KB, r7-verified unit layout
// (linear for global_load_lds, conflict-free ds_read_b128, 0 conflicts
// measured). Grid 1024, XCD-banded (proven: FETCH 49-58 MB < 67 MB of x).
__global__ __launch_bounds__(256, 2) void gemm_fused(const float* __restrict__ x,
                                                     const float* __restrict__ theta,
                                                     const unsigned short* __restrict__ Bt,
                                                     const float* __restrict__ bias,
                                                     float* __restrict__ C) {
  __shared__ unsigned short Bs[4 * 4096];  // 32 KB: units [p][kh]
  const int tid = threadIdx.x;

  const int L = blockIdx.x;             // 0..1023
  const int xcd = L & 7;
  const int idx = L >> 3;               // 0..127
  const int by = xcd * 16 + (idx >> 3); // M-tile 0..127, banded per XCD
  const int bx = idx & 7;               // N-tile 0..7
  const int m0 = by * 128;
  const int n0 = bx * 128;

  const int lane = tid & 63;
  const int wave = tid >> 6;        // 0..3
  const int wm = wave * 32;         // wave tile 32(M) x 128(N)
  const int fr = lane & 15;
  const int fq = lane >> 4;

  f32x4 acc[2][8] = {};

  // ---- B staging (r7/r8-verified machinery) ----
  const int srow = ((tid >> 5) << 3) | (tid & 7);  // 0..63
  const int kc = (tid >> 3) & 3;
  const unsigned short* Bg = Bt + (long)(n0 + srow) * K_DIM + kc * 8;
  unsigned short* BsD = Bs + tid * 8;

#define STAGEB(P, T) do { \
    _Pragma("unroll") \
    for (int kh = 0; kh < 2; ++kh) \
      _Pragma("unroll") \
      for (int i2 = 0; i2 < 2; ++i2) \
        GLD_LDS(Bg + (long)i2 * 64 * K_DIM + (T) * 64 + kh * 32, \
                BsD + ((P) * 2 + kh) * 4096 + i2 * 2048); \
  } while (0)

  // ---- x/theta prefetch: plain loads + memory-fence pin ----
  // row(i) = m0 + wm + i*16 + fr ; cols = t*64 + kh*32 + fq*8 + (0..7).
  const float* xp0 = x + (long)(m0 + wm + fr) * K_DIM + fq * 8;  // i=0
  const float* xp1 = xp0 + (long)16 * K_DIM;                     // i=1

  float4 xaE[2][2][2], xaO[2][2][2];  // [i][kh][half], even/odd tile sets
  float4 thE[2][2],    thO[2][2];     // [kh][half]
  short8 af[2][2];                    // [i][kh] packed bf16 A-frags

#define LOADX_SET(XA, TH, T) do { \
    _Pragma("unroll") \
    for (int i = 0; i < 2; ++i) \
      _Pragma("unroll") \
      for (int kh = 0; kh < 2; ++kh) { \
        const float* g_ = (i ? xp1 : xp0) + (long)(T) * 64 + kh * 32; \
        XA[i][kh][0] = *(const float4*)(g_); \
        XA[i][kh][1] = *(const float4*)(g_ + 4); \
      } \
    _Pragma("unroll") \
    for (int kh = 0; kh < 2; ++kh) { \
      TH[kh][0] = *(const float4*)(theta + (T) * 64 + kh * 32 + fq * 8); \
      TH[kh][1] = *(const float4*)(theta + (T) * 64 + kh * 32 + fq * 8 + 4); \
    } \
  } while (0)

  // IR-level pin: loads above cannot sink past a may-write-memory asm.
#define FENCE() do { asm volatile("" ::: "memory"); \
                     __builtin_amdgcn_sched_barrier(0); } while (0)

#define CONVA(XA, TH) do { \
    _Pragma("unroll") \
    for (int kh = 0; kh < 2; ++kh) \
      _Pragma("unroll") \
      for (int i = 0; i < 2; ++i) { \
        union { unsigned short s[8]; short8 v; } o; \
        o.s[0] = f2bf(__cosf(XA[i][kh][0].x + TH[kh][0].x)); \
        o.s[1] = f2bf(__cosf(XA[i][kh][0].y + TH[kh][0].y)); \
        o.s[2] = f2bf(__cosf(XA[i][kh][0].z + TH[kh][0].z)); \
        o.s[3] = f2bf(__cosf(XA[i][kh][0].w + TH[kh][0].w)); \
        o.s[4] = f2bf(__cosf(XA[i][kh][1].x + TH[kh][1].x)); \
        o.s[5] = f2bf(__cosf(XA[i][kh][1].y + TH[kh][1].y)); \
        o.s[6] = f2bf(__cosf(XA[i][kh][1].z + TH[kh][1].z)); \
        o.s[7] = f2bf(__cosf(XA[i][kh][1].w + TH[kh][1].w)); \
        af[i][kh] = o.v; \
      } \
  } while (0)

  // B fragment read base: elem(row=j*16+fr, kc=fq) = j*512 + baseB.
  const int baseB = (fr >> 3) * 256 + fq * 64 + (fr & 7) * 8;

#define COMPUTE(P) do { \
    _Pragma("unroll") \
    for (int kh = 0; kh < 2; ++kh) { \
      const unsigned short* Bu = Bs + ((P) * 2 + kh) * 4096; \
      _Pragma("unroll") \
      for (int j = 0; j < 8; ++j) { \
        short8 bf = *(const short8*)(Bu + baseB + j * 512); \
        acc[0][j] = __builtin_amdgcn_mfma_f32_16x16x32_bf16(af[0][kh], bf, acc[0][j], 0, 0, 0); \
        acc[1][j] = __builtin_amdgcn_mfma_f32_16x16x32_bf16(af[1][kh], bf, acc[1][j], 0, 0, 0); \
      } \
    } \
  } while (0)

#define VMW0() asm volatile("s_waitcnt vmcnt(0)" ::: "memory")

  // Prologue: tile 0 -> set E, parity 0.
  LOADX_SET(xaE, thE, 0);
  STAGEB(0, 0);
  FENCE();

  for (int t = 0; t < 14; t += 2) {
    // even tile t (set E, parity 0); prefetch t+1 -> set O, parity 1
    VMW0();
    __syncthreads();
    LOADX_SET(xaO, thO, t + 1);
    STAGEB(1, t + 1);
    FENCE();
    CONVA(xaE, thE);
    COMPUTE(0);
    // odd tile t+1 (set O, parity 1); prefetch t+2 -> set E, parity 0
    VMW0();
    __syncthreads();
    LOADX_SET(xaE, thE, t + 2);
    STAGEB(0, t + 2);
    FENCE();
    CONVA(xaO, thO);
    COMPUTE(1);
  }
  { // t = 14 (set E, parity 0); prefetch 15 -> set O, parity 1
    VMW0();
    __syncthreads();
    LOADX_SET(xaO, thO, 15);
    STAGEB(1, 15);
    FENCE();
    CONVA(xaE, thE);
    COMPUTE(0);
  }
  { // t = 15 (set O, parity 1); no prefetch
    VMW0();
    __syncthreads();
    CONVA(xaO, thO);
    COMPUTE(1);
  }

  // Epilogue: D[row=(lane>>4)*4+r][col=lane&15] per 16x16 frag (m89-verified).
  const int cn = lane & 15;
  const int rq = fq * 4;
#pragma unroll
  for (int j = 0; j < 8; ++j) {
    const int n = n0 + j * 16 + cn;
    const float bv = bias[n];
#pragma unroll
    for (int i = 0; i < 2; ++i) {
      const long mb = (long)(m0 + wm + i * 16 + rq) * N_DIM + n;
#pragma unroll
      for (int r = 0; r < 4; ++r)
        C[mb + (long)r * N_DIM] = acc[i][j][r] + bv;
    }
  }
}

extern "C" void kernel_launch(void* const* d_in, const int* in_sizes, int n_in,
                              void* d_out, int out_size, void* d_ws, size_t ws_size,
                              hipStream_t stream) {
  const float* x = (const float*)d_in[0];      // [8,2048,1024]
  const float* theta = (const float*)d_in[1];  // [128,8] -> flat 1024
  const float* W = (const float*)d_in[2];      // [1024,1024]
  const float* b = (const float*)d_in[3];      // [1024]
  float* out = (float*)d_out;                  // [8,2048,1024] f32

  unsigned short* Wbf = (unsigned short*)d_ws;  // 2 MB

  hipLaunchKernelGGL(prep_w, dim3(PREP_W_BLOCKS), dim3(256), 0, stream, W, Wbf);
  hipLaunchKernelGGL(gemm_fused, dim3(M_DIM / 128 * (N_DIM / 128)), dim3(256), 0,
                     stream, x, theta, Wbf, b, out);
}

// Round 10
// 153.413 us; speedup vs baseline: 1.3663x; 1.3663x over previous
//
#include <hip/hip_runtime.h>
#include <hip/hip_bf16.h>
#include <stdint.h>

// Problem constants (B=8, S=2048, E=1024, H=128, DK=8)
#define M_DIM 16384   // B*S
#define N_DIM 1024    // E (output features)
#define K_DIM 1024    // E (reduction)

typedef __attribute__((ext_vector_type(8))) short short8;
typedef __attribute__((ext_vector_type(4))) float f32x4;

// async global->LDS, 16B per lane. LDS dest must be wave-uniform base + lane*16.
#define GLD_LDS(g, l) __builtin_amdgcn_global_load_lds( \
    (const __attribute__((address_space(1))) unsigned int*)(g), \
    (__attribute__((address_space(3))) unsigned int*)(l), 16, 0, 0)

__device__ __forceinline__ unsigned short f2bf(float f) {
  union { float f; unsigned int u; } v;
  v.f = f;
  unsigned int u = v.u + 0x7FFFu + ((v.u >> 16) & 1u);  // RNE
  return (unsigned short)(u >> 16);
}

// Fused prep: blocks [0, 8192) -> A_bf16[m,k] = bf16(cos(x[m,k]+theta[k]));
//             blocks [8192, 8704) -> W_bf16 cast. 8 elems/thread, all 16B I/O.
// Measured r2: ~18 us at ~6 TB/s (BW roofline for its 107 MB of traffic).
#define PREP_A_BLOCKS (M_DIM * K_DIM / (256 * 8))   // 8192
#define PREP_W_BLOCKS (N_DIM * K_DIM / (256 * 8))   // 512
__global__ __launch_bounds__(256) void prep_all(const float* __restrict__ x,
                                                const float* __restrict__ theta,
                                                const float* __restrict__ W,
                                                unsigned short* __restrict__ A,
                                                unsigned short* __restrict__ Wb) {
  if (blockIdx.x < PREP_A_BLOCKS) {
    const long i = ((long)blockIdx.x * 256 + threadIdx.x) * 8;
    const int k = (int)(i & (K_DIM - 1));
    float4 x0 = *(const float4*)(x + i);
    float4 x1 = *(const float4*)(x + i + 4);
    float4 t0 = *(const float4*)(theta + k);
    float4 t1 = *(const float4*)(theta + k + 4);
    union { unsigned short s[8]; short8 v; } o;
    o.s[0] = f2bf(__cosf(x0.x + t0.x));
    o.s[1] = f2bf(__cosf(x0.y + t0.y));
    o.s[2] = f2bf(__cosf(x0.z + t0.z));
    o.s[3] = f2bf(__cosf(x0.w + t0.w));
    o.s[4] = f2bf(__cosf(x1.x + t1.x));
    o.s[5] = f2bf(__cosf(x1.y + t1.y));
    o.s[6] = f2bf(__cosf(x1.z + t1.z));
    o.s[7] = f2bf(__cosf(x1.w + t1.w));
    *(short8*)(A + i) = o.v;
  } else {
    const long i = ((long)(blockIdx.x - PREP_A_BLOCKS) * 256 + threadIdx.x) * 8;
    float4 w0 = *(const float4*)(W + i);
    float4 w1 = *(const float4*)(W + i + 4);
    union { unsigned short s[8]; short8 v; } o;
    o.s[0] = f2bf(w0.x); o.s[1] = f2bf(w0.y); o.s[2] = f2bf(w0.z); o.s[3] = f2bf(w0.w);
    o.s[4] = f2bf(w1.x); o.s[5] = f2bf(w1.y); o.s[6] = f2bf(w1.z); o.s[7] = f2bf(w1.w);
    *(short8*)(Wb + i) = o.v;
  }
}

// C[m,n] = sum_k A[m,k]*Bt[n,k] + bias[n].  A:[M,K] bf16, Bt:[N,K] bf16, C:[M,N] f32.
//
// R11 = exact revert to the session-best r2 kernel (measured: 48.7-51 us,
// MfmaUtil 25%, 0 bank conflicts, FETCH 24.6 MB (A L3-resident from prep),
// WRITE 72 MB). 256x256 tile, BK=64, 8 waves (2M x 4N, 128x64 per wave),
// 512 threads. LDS 128 KB double-buffered. 2-deep counted-vmcnt pipeline:
// tile t+1's 8 global_load_lds issued before computing tile t; vmcnt(8)
// (never 0 in steady state) + raw s_barrier. Verified vs alternatives this
// session: coarse 8-phase (r4, 55 us), fine 8-phase (r6, 50 us), all fused
// variants (122-125 us) -- this structure is the best measured.
//
// Grid: 256 blocks = exactly 1/CU (128 KB LDS). XCD-banded map: linear id L,
// XCD c = L&7 owns M-tiles [8c, 8c+8); the 4 N-blocks of an M-tile are
// adjacent in dispatch (share the A panel in that XCD's L2).
__global__ __launch_bounds__(512, 2) void gemm_bt(const unsigned short* __restrict__ A,
                                                  const unsigned short* __restrict__ Bt,
                                                  const float* __restrict__ bias,
                                                  float* __restrict__ C) {
  constexpr int BM = 256, BN = 256, BK = 64;
  constexpr int NT = K_DIM / BK;  // 16
  __shared__ unsigned short As[2 * BM * BK];  // 64 KB (2 buffers)
  __shared__ unsigned short Bs[2 * BN * BK];  // 64 KB
  const int tid = threadIdx.x;

  const int L = blockIdx.y * 4 + blockIdx.x;  // linear dispatch id, 0..255
  const int xcd = L & 7;
  const int idx = L >> 3;                     // 0..31 within XCD
  const int by = xcd * 8 + (idx >> 2);        // M-tile 0..63, banded per XCD
  const int bx = idx & 3;                     // N-tile 0..3
  const int m0 = by * BM;
  const int n0 = bx * BN;

  const int lane = tid & 63;
  const int wave = tid >> 6;        // 0..7
  const int wm = (wave >> 2) * 128; // wave tile origin in M (0,128)
  const int wn = (wave & 3) * 64;   // wave tile origin in N (0,64,128,192)

  f32x4 acc[8][4] = {};

  // Staging: per issue i (0..3), thread t fills LDS slot d = i*512 + t
  // (8 bf16 chunk). row = d>>3 = i*64 + (t>>3); source chunk is XOR-swizzled:
  // LDS[row][slot s] = global[row][s ^ (row&7)]. row&7 == (t>>3)&7 for all i.
  const int csw = (tid & 7) ^ ((tid >> 3) & 7);
  const unsigned short* Ag = A + (long)(m0 + (tid >> 3)) * K_DIM + csw * 8;
  const unsigned short* Bg = Bt + (long)(n0 + (tid >> 3)) * K_DIM + csw * 8;
  unsigned short* Asd = As + tid * 8;
  unsigned short* Bsd = Bs + tid * 8;

  // prologue: stage tile 0 into buffer 0
#pragma unroll
  for (int i = 0; i < 4; ++i) GLD_LDS(Ag + (long)i * 64 * K_DIM, Asd + i * 4096);
#pragma unroll
  for (int i = 0; i < 4; ++i) GLD_LDS(Bg + (long)i * 64 * K_DIM, Bsd + i * 4096);
  Ag += BK;
  Bg += BK;

  for (int t = 0; t < NT; ++t) {
    const int cur = t & 1;
    if (t < NT - 1) {
      // issue next tile's 8 loads into the other buffer (not waited here)
      unsigned short* Ad = Asd + (cur ^ 1) * (BM * BK);
      unsigned short* Bd = Bsd + (cur ^ 1) * (BN * BK);
#pragma unroll
      for (int i = 0; i < 4; ++i) GLD_LDS(Ag + (long)i * 64 * K_DIM, Ad + i * 4096);
#pragma unroll
      for (int i = 0; i < 4; ++i) GLD_LDS(Bg + (long)i * 64 * K_DIM, Bd + i * 4096);
      Ag += BK;
      Bg += BK;
      asm volatile("s_waitcnt vmcnt(8)" ::: "memory");  // tile t landed (per-wave)
    } else {
      asm volatile("s_waitcnt vmcnt(0)" ::: "memory");  // last tile: drain
    }
    __builtin_amdgcn_s_barrier();  // all waves' portions of buf[cur] visible
    asm volatile("" ::: "memory");

    const unsigned short* SA = As + cur * (BM * BK);
    const unsigned short* SB = Bs + cur * (BN * BK);
#pragma unroll
    for (int s = 0; s < 2; ++s) {
      // chunk slot for this lane: (k-chunk) ^ (row&7); row&7 == lane&7 for all
      // frag rows (wm, wn, i*16 are multiples of 8/16).
      const int fr = lane & 15;
      const int fq = lane >> 4;
      const int swz = (((s * 4 + fq) ^ (lane & 7)) * 8);
      short8 af[8], bf[4];
#pragma unroll
      for (int j = 0; j < 4; ++j)
        bf[j] = *(const short8*)(SB + (wn + j * 16 + fr) * BK + swz);
#pragma unroll
      for (int i = 0; i < 8; ++i)
        af[i] = *(const short8*)(SA + (wm + i * 16 + fr) * BK + swz);
#pragma unroll
      for (int i = 0; i < 8; ++i)
#pragma unroll
        for (int j = 0; j < 4; ++j)
          acc[i][j] = __builtin_amdgcn_mfma_f32_16x16x32_bf16(af[i], bf[j], acc[i][j], 0, 0, 0);
    }
    asm volatile("" ::: "memory");
    __builtin_amdgcn_s_barrier();  // all reads of buf[cur] done -> reusable
    asm volatile("" ::: "memory");
  }

  // Epilogue: D[row=(lane>>4)*4+r][col=lane&15] per 16x16 frag (m89-verified).
  const int cn = lane & 15;
  const int rq = (lane >> 4) * 4;
#pragma unroll
  for (int j = 0; j < 4; ++j) {
    const int n = n0 + wn + j * 16 + cn;
    const float bv = bias[n];
#pragma unroll
    for (int i = 0; i < 8; ++i) {
      const long mb = (long)(m0 + wm + i * 16 + rq) * N_DIM + n;
#pragma unroll
      for (int r = 0; r < 4; ++r)
        C[mb + (long)r * N_DIM] = acc[i][j][r] + bv;
    }
  }
}

extern "C" void kernel_launch(void* const* d_in, const int* in_sizes, int n_in,
                              void* d_out, int out_size, void* d_ws, size_t ws_size,
                              hipStream_t stream) {
  const float* x = (const float*)d_in[0];      // [8,2048,1024]
  const float* theta = (const float*)d_in[1];  // [128,8] -> flat 1024
  const float* W = (const float*)d_in[2];      // [1024,1024]
  const float* b = (const float*)d_in[3];      // [1024]
  float* out = (float*)d_out;                  // [8,2048,1024] f32

  unsigned short* Abf = (unsigned short*)d_ws;                   // 33.5 MB
  unsigned short* Wbf = Abf + (size_t)M_DIM * K_DIM;             // +2 MB

  hipLaunchKernelGGL(prep_all, dim3(PREP_A_BLOCKS + PREP_W_BLOCKS), dim3(256), 0,
                     stream, x, theta, W, Abf, Wbf);
  hipLaunchKernelGGL(gemm_bt, dim3(N_DIM / 256, M_DIM / 256), dim3(512), 0, stream,
                     Abf, Wbf, b, out);
}